// Round 2
// 431.538 us; speedup vs baseline: 1.1545x; 1.1545x over previous
//
#include <hip/hip_runtime.h>

#define NPIX (8 * 1024 * 1024)
#define IN 8
#define HID 16
#define OUTC 3
#define BLK 256
#define PPT 2   // pixels per thread

// f16x2 pair type for v_dot2_f32_f16 (fdot2 accepts _Float16 vectors;
// cvt_pkrtz returns __fp16 vectors -> bit_cast between them, both 4 B).
typedef _Float16 f16x2 __attribute__((ext_vector_type(2)));

__device__ __forceinline__ f16x2 pkrtz(float lo, float hi) {
    return __builtin_bit_cast(f16x2, __builtin_amdgcn_cvt_pkrtz(lo, hi));
}

// d_ws layout (u32-indexed):
// [0] mask-format flag; weights transposed + packed as f16x2 pairs so each
// output-neuron row is contiguous -> uniform s_load_dwordx4/x8 into SGPRs.
#define WS_W0H 16    // 16 rows x 4 u32   (w0^T, f16 pairs over IN)
#define WS_W1H 80    // 16 rows x 8 u32   (w1^T, f16 pairs over HID)
#define WS_W2H 208   //  3 rows x 8 u32   (w2^T)
#define WS_B0  240   // f32 x16
#define WS_B1  256   // f32 x16
#define WS_B2  272   // f32 x3

__device__ __forceinline__ unsigned int pack2(float lo, float hi) {
    // RNE f32->f16 for weights (done once in prep, so precision > speed here)
    _Float16 a = (_Float16)lo, b = (_Float16)hi;
    unsigned short ua = __builtin_bit_cast(unsigned short, a);
    unsigned short ub = __builtin_bit_cast(unsigned short, b);
    return (unsigned int)ua | ((unsigned int)ub << 16);
}

__global__ void prep_kernel(const unsigned int* __restrict__ m,
                            const float* __restrict__ w0, const float* __restrict__ b0,
                            const float* __restrict__ w1, const float* __restrict__ b1,
                            const float* __restrict__ w2, const float* __restrict__ b2,
                            float* __restrict__ ws) {
    const int t = threadIdx.x;  // 256
    unsigned int* wsu = (unsigned int*)ws;
    if (t < 64) {  // mask format detect: packed bool bytes give u32 words > 1 a.s.
        unsigned int acc = 0u;
        #pragma unroll
        for (int k = 0; k < 8; ++k) acc |= m[t * 8 + k];
        const unsigned long long big = __ballot(acc > 1u);
        if (t == 0) ((int*)ws)[0] = big ? 1 : 0;   // 1 => byte-mask
    }
    if (t < 64)  { int j = t >> 2, k = t & 3;
        wsu[WS_W0H + j * 4 + k] = pack2(w0[(2 * k) * HID + j], w0[(2 * k + 1) * HID + j]); }
    if (t < 128) { int j = t >> 3, k = t & 7;
        wsu[WS_W1H + j * 8 + k] = pack2(w1[(2 * k) * HID + j], w1[(2 * k + 1) * HID + j]); }
    if (t < 24)  { int j = t >> 3, k = t & 7;
        wsu[WS_W2H + j * 8 + k] = pack2(w2[(2 * k) * OUTC + j], w2[(2 * k + 1) * OUTC + j]); }
    if (t < HID)  { ws[WS_B0 + t] = b0[t]; ws[WS_B1 + t] = b1[t]; }
    if (t < OUTC) { ws[WS_B2 + t] = b2[t]; }
}

// __launch_bounds__(256, 2): min-waves FLOOR of 2/EU -> ~256-VGPR budget so the
// h0/h1 arrays live in arch VGPRs (round-0 kernel sat at 40 VGPRs with the
// ~80-value live set shuffled through AGPRs via v_accvgpr_* = VALU overhead).
// 2 waves/EU = 8 waves/CU is plenty of TLP for straight-line dual-pixel FMA chains.
__global__ void __launch_bounds__(BLK, 2) colormlp_kernel(
    const float* __restrict__ x,
    const void*  __restrict__ mask,
    const float* __restrict__ ws,
    float* __restrict__ out)
{
    __shared__ __align__(16) float sOut[BLK * PPT * OUTC];

    const int t = threadIdx.x;
    const unsigned int* wsu = (const unsigned int*)ws;
    const int mflag = ((const int*)ws)[0];

    const unsigned int pix0 = (blockIdx.x * BLK + t) * PPT;

    // ---- load x: 2 consecutive pixels x 8 ch = 64 B contiguous per lane ----
    float4 x0[PPT], x1[PPT];
    {
        const float4* xp = (const float4*)(x + (size_t)pix0 * IN);
        #pragma unroll
        for (int p = 0; p < PPT; ++p) { x0[p] = xp[2 * p]; x1[p] = xp[2 * p + 1]; }
    }

    // ---- pack x to f16 pairs (v_cvt_pkrtz, 4/pixel) ----
    f16x2 xh[PPT][4];
    #pragma unroll
    for (int p = 0; p < PPT; ++p) {
        xh[p][0] = pkrtz(x0[p].x, x0[p].y);
        xh[p][1] = pkrtz(x0[p].z, x0[p].w);
        xh[p][2] = pkrtz(x1[p].x, x1[p].y);
        xh[p][3] = pkrtz(x1[p].z, x1[p].w);
    }

    // ---- layer 0: h0 = relu(x @ w0 + b0), f16 dot2 pairs, f32 accumulate ----
    f16x2 h0h[PPT][HID / 2];
    {
        float h0[PPT][HID];
        #pragma unroll
        for (int j = 0; j < HID; ++j) {
            f16x2 w[4];
            #pragma unroll
            for (int k = 0; k < 4; ++k) w[k] = __builtin_bit_cast(f16x2, wsu[WS_W0H + j * 4 + k]);
            const float bj = ws[WS_B0 + j];
            #pragma unroll
            for (int p = 0; p < PPT; ++p) {
                float acc = bj;
                #pragma unroll
                for (int k = 0; k < 4; ++k) acc = __builtin_amdgcn_fdot2(xh[p][k], w[k], acc, false);
                h0[p][j] = fmaxf(acc, 0.0f);
            }
        }
        #pragma unroll
        for (int p = 0; p < PPT; ++p)
            #pragma unroll
            for (int i = 0; i < HID / 2; ++i)
                h0h[p][i] = pkrtz(h0[p][2 * i], h0[p][2 * i + 1]);
    }

    // ---- layer 1: h1 = relu(h0 @ w1 + b1) ----
    f16x2 h1h[PPT][HID / 2];
    {
        float h1[PPT][HID];
        #pragma unroll
        for (int j = 0; j < HID; ++j) {
            f16x2 w[8];
            #pragma unroll
            for (int k = 0; k < 8; ++k) w[k] = __builtin_bit_cast(f16x2, wsu[WS_W1H + j * 8 + k]);
            const float bj = ws[WS_B1 + j];
            #pragma unroll
            for (int p = 0; p < PPT; ++p) {
                float acc = bj;
                #pragma unroll
                for (int k = 0; k < 8; ++k) acc = __builtin_amdgcn_fdot2(h0h[p][k], w[k], acc, false);
                h1[p][j] = fmaxf(acc, 0.0f);
            }
        }
        #pragma unroll
        for (int p = 0; p < PPT; ++p)
            #pragma unroll
            for (int i = 0; i < HID / 2; ++i)
                h1h[p][i] = pkrtz(h1[p][2 * i], h1[p][2 * i + 1]);
    }

    // ---- mask load (uniform branch on detected layout) ----
    int mv[PPT];
    if (mflag) {
        uchar2 m2 = *(const uchar2*)((const unsigned char*)mask + pix0);
        mv[0] = m2.x; mv[1] = m2.y;
    } else {
        int2 m2 = *(const int2*)((const int*)mask + pix0);
        mv[0] = m2.x; mv[1] = m2.y;
    }

    // ---- layer 2 + sigmoid + blend (blend kept in exact f32) ----
    #pragma unroll
    for (int p = 0; p < PPT; ++p) {
        const float res = x0[p].w;
        float ov[OUTC];
        #pragma unroll
        for (int j = 0; j < OUTC; ++j) {
            float acc = ws[WS_B2 + j];
            #pragma unroll
            for (int k = 0; k < 8; ++k)
                acc = __builtin_amdgcn_fdot2(h1h[p][k],
                        __builtin_bit_cast(f16x2, wsu[WS_W2H + j * 8 + k]), acc, false);
            float e = __expf(-acc);
            float y = __builtin_amdgcn_rcpf(1.0f + e);
            float rgb = (j == 0) ? x0[p].x : (j == 1) ? x0[p].y : x0[p].z;
            float bl = fmaf(res, y - rgb, rgb);      // (1-res)*rgb + res*y
            ov[j] = mv[p] ? bl : 0.0f;
        }
        float* sp = sOut + (size_t)(t * PPT + p) * OUTC;
        ((float2*)sp)[0] = make_float2(ov[0], ov[1]);
        sp[2] = ov[2];
    }
    __syncthreads();

    // ---- contiguous wave-level stores: 384 float4 = 6 KB per block ----
    {
        const float4* s4 = (const float4*)sOut;
        float4* o4 = (float4*)(out + (size_t)blockIdx.x * (BLK * PPT * OUTC));
        o4[t] = s4[t];
        if (t < (BLK * PPT * OUTC) / 4 - BLK) o4[BLK + t] = s4[BLK + t];
    }
}

extern "C" void kernel_launch(void* const* d_in, const int* in_sizes, int n_in,
                              void* d_out, int out_size, void* d_ws, size_t ws_size,
                              hipStream_t stream) {
    const float* x    = (const float*)d_in[0];
    const void*  mask = d_in[1];
    const float* w0   = (const float*)d_in[2];
    const float* b0   = (const float*)d_in[3];
    const float* w1   = (const float*)d_in[4];
    const float* b1   = (const float*)d_in[5];
    const float* w2   = (const float*)d_in[6];
    const float* b2   = (const float*)d_in[7];
    float* out = (float*)d_out;
    float* ws  = (float*)d_ws;

    prep_kernel<<<1, BLK, 0, stream>>>((const unsigned int*)mask,
                                       w0, b0, w1, b1, w2, b2, ws);

    const int grid = NPIX / (BLK * PPT);  // 16384
    colormlp_kernel<<<grid, BLK, 0, stream>>>(x, mask, ws, out);
}

// Round 4
// 431.112 us; speedup vs baseline: 1.1556x; 1.0010x over previous
//
#include <hip/hip_runtime.h>

#define NPIX (8 * 1024 * 1024)
#define IN 8
#define HID 16
#define OUTC 3
#define BLK 256
#define PPT 2   // pixels per thread

// f16x2 pair type for v_dot2_f32_f16 (fdot2 accepts _Float16 vectors;
// cvt_pkrtz returns __fp16 vectors -> bit_cast between them, both 4 B).
typedef _Float16 f16x2 __attribute__((ext_vector_type(2)));

__device__ __forceinline__ f16x2 pkrtz(float lo, float hi) {
    return __builtin_bit_cast(f16x2, __builtin_amdgcn_cvt_pkrtz(lo, hi));
}

// d_ws layout (u32-indexed):
// [0] mask-format flag; weights transposed + packed as f16x2 pairs so each
// output-neuron row is contiguous -> uniform s_load_dwordx4/x8 into SGPRs.
#define WS_W0H 16    // 16 rows x 4 u32   (w0^T, f16 pairs over IN)
#define WS_W1H 80    // 16 rows x 8 u32   (w1^T, f16 pairs over HID)
#define WS_W2H 208   //  3 rows x 8 u32   (w2^T)
#define WS_B0  240   // f32 x16
#define WS_B1  256   // f32 x16
#define WS_B2  272   // f32 x3

__device__ __forceinline__ unsigned int pack2(float lo, float hi) {
    // RNE f32->f16 for weights (done once in prep, so precision > speed here)
    _Float16 a = (_Float16)lo, b = (_Float16)hi;
    unsigned short ua = __builtin_bit_cast(unsigned short, a);
    unsigned short ub = __builtin_bit_cast(unsigned short, b);
    return (unsigned int)ua | ((unsigned int)ub << 16);
}

__global__ void prep_kernel(const unsigned int* __restrict__ m,
                            const float* __restrict__ w0, const float* __restrict__ b0,
                            const float* __restrict__ w1, const float* __restrict__ b1,
                            const float* __restrict__ w2, const float* __restrict__ b2,
                            float* __restrict__ ws) {
    const int t = threadIdx.x;  // 256
    unsigned int* wsu = (unsigned int*)ws;
    if (t < 64) {  // mask format detect: packed bool bytes give u32 words > 1 a.s.
        unsigned int acc = 0u;
        #pragma unroll
        for (int k = 0; k < 8; ++k) acc |= m[t * 8 + k];
        const unsigned long long big = __ballot(acc > 1u);
        if (t == 0) ((int*)ws)[0] = big ? 1 : 0;   // 1 => byte-mask
    }
    if (t < 64)  { int j = t >> 2, k = t & 3;
        wsu[WS_W0H + j * 4 + k] = pack2(w0[(2 * k) * HID + j], w0[(2 * k + 1) * HID + j]); }
    if (t < 128) { int j = t >> 3, k = t & 7;
        wsu[WS_W1H + j * 8 + k] = pack2(w1[(2 * k) * HID + j], w1[(2 * k + 1) * HID + j]); }
    if (t < 24)  { int j = t >> 3, k = t & 7;
        wsu[WS_W2H + j * 8 + k] = pack2(w2[(2 * k) * OUTC + j], w2[(2 * k + 1) * OUTC + j]); }
    if (t < HID)  { ws[WS_B0 + t] = b0[t]; ws[WS_B1 + t] = b1[t]; }
    if (t < OUTC) { ws[WS_B2 + t] = b2[t]; }
}

// __launch_bounds__(256, 4): 4 waves/EU (16/CU), 128-VGPR budget. Round-2's
// (256,2) left only 2 waves/SIMD -> uncovered HBM latency (~140 us vs ~65 us
// memory floor). f16 live set is ~80 VGPRs, fits 128 with no spill.
__global__ void __launch_bounds__(BLK, 4) colormlp_kernel(
    const float* __restrict__ x,
    const void*  __restrict__ mask,
    const float* __restrict__ ws,
    float* __restrict__ out)
{
    __shared__ __align__(16) float sOut[BLK * PPT * OUTC];

    const int t = threadIdx.x;
    const unsigned int* wsu = (const unsigned int*)ws;
    const int mflag = ((const int*)ws)[0];

    const unsigned int pix0 = (blockIdx.x * BLK + t) * PPT;

    // ---- load x: 2 consecutive pixels x 8 ch = 64 B contiguous per lane ----
    float4 x0[PPT], x1[PPT];
    {
        const float4* xp = (const float4*)(x + (size_t)pix0 * IN);
        #pragma unroll
        for (int p = 0; p < PPT; ++p) { x0[p] = xp[2 * p]; x1[p] = xp[2 * p + 1]; }
    }

    // ---- pack x to f16 pairs (v_cvt_pkrtz, 4/pixel) ----
    f16x2 xh[PPT][4];
    #pragma unroll
    for (int p = 0; p < PPT; ++p) {
        xh[p][0] = pkrtz(x0[p].x, x0[p].y);
        xh[p][1] = pkrtz(x0[p].z, x0[p].w);
        xh[p][2] = pkrtz(x1[p].x, x1[p].y);
        xh[p][3] = pkrtz(x1[p].z, x1[p].w);
    }

    // ---- layer 0: h0 = relu(x @ w0 + b0), f16 dot2 pairs, f32 accumulate ----
    f16x2 h0h[PPT][HID / 2];
    {
        float h0[PPT][HID];
        #pragma unroll
        for (int j = 0; j < HID; ++j) {
            f16x2 w[4];
            #pragma unroll
            for (int k = 0; k < 4; ++k) w[k] = __builtin_bit_cast(f16x2, wsu[WS_W0H + j * 4 + k]);
            const float bj = ws[WS_B0 + j];
            #pragma unroll
            for (int p = 0; p < PPT; ++p) {
                float acc = bj;
                #pragma unroll
                for (int k = 0; k < 4; ++k) acc = __builtin_amdgcn_fdot2(xh[p][k], w[k], acc, false);
                h0[p][j] = fmaxf(acc, 0.0f);
            }
        }
        #pragma unroll
        for (int p = 0; p < PPT; ++p)
            #pragma unroll
            for (int i = 0; i < HID / 2; ++i)
                h0h[p][i] = pkrtz(h0[p][2 * i], h0[p][2 * i + 1]);
    }

    // ---- layer 1: h1 = relu(h0 @ w1 + b1) ----
    f16x2 h1h[PPT][HID / 2];
    {
        float h1[PPT][HID];
        #pragma unroll
        for (int j = 0; j < HID; ++j) {
            f16x2 w[8];
            #pragma unroll
            for (int k = 0; k < 8; ++k) w[k] = __builtin_bit_cast(f16x2, wsu[WS_W1H + j * 8 + k]);
            const float bj = ws[WS_B1 + j];
            #pragma unroll
            for (int p = 0; p < PPT; ++p) {
                float acc = bj;
                #pragma unroll
                for (int k = 0; k < 8; ++k) acc = __builtin_amdgcn_fdot2(h0h[p][k], w[k], acc, false);
                h1[p][j] = fmaxf(acc, 0.0f);
            }
        }
        #pragma unroll
        for (int p = 0; p < PPT; ++p)
            #pragma unroll
            for (int i = 0; i < HID / 2; ++i)
                h1h[p][i] = pkrtz(h1[p][2 * i], h1[p][2 * i + 1]);
    }

    // ---- mask load (uniform branch on detected layout) ----
    int mv[PPT];
    if (mflag) {
        uchar2 m2 = *(const uchar2*)((const unsigned char*)mask + pix0);
        mv[0] = m2.x; mv[1] = m2.y;
    } else {
        int2 m2 = *(const int2*)((const int*)mask + pix0);
        mv[0] = m2.x; mv[1] = m2.y;
    }

    // ---- layer 2 + sigmoid + blend (blend kept in exact f32) ----
    #pragma unroll
    for (int p = 0; p < PPT; ++p) {
        const float res = x0[p].w;
        float ov[OUTC];
        #pragma unroll
        for (int j = 0; j < OUTC; ++j) {
            float acc = ws[WS_B2 + j];
            #pragma unroll
            for (int k = 0; k < 8; ++k)
                acc = __builtin_amdgcn_fdot2(h1h[p][k],
                        __builtin_bit_cast(f16x2, wsu[WS_W2H + j * 8 + k]), acc, false);
            float e = __expf(-acc);
            float y = __builtin_amdgcn_rcpf(1.0f + e);
            float rgb = (j == 0) ? x0[p].x : (j == 1) ? x0[p].y : x0[p].z;
            float bl = fmaf(res, y - rgb, rgb);      // (1-res)*rgb + res*y
            ov[j] = mv[p] ? bl : 0.0f;
        }
        float* sp = sOut + (size_t)(t * PPT + p) * OUTC;
        ((float2*)sp)[0] = make_float2(ov[0], ov[1]);
        sp[2] = ov[2];
    }
    __syncthreads();

    // ---- contiguous wave-level stores: 384 float4 = 6 KB per block ----
    {
        const float4* s4 = (const float4*)sOut;
        float4* o4 = (float4*)(out + (size_t)blockIdx.x * (BLK * PPT * OUTC));
        o4[t] = s4[t];
        if (t < (BLK * PPT * OUTC) / 4 - BLK) o4[BLK + t] = s4[BLK + t];
    }
}

extern "C" void kernel_launch(void* const* d_in, const int* in_sizes, int n_in,
                              void* d_out, int out_size, void* d_ws, size_t ws_size,
                              hipStream_t stream) {
    const float* x    = (const float*)d_in[0];
    const void*  mask = d_in[1];
    const float* w0   = (const float*)d_in[2];
    const float* b0   = (const float*)d_in[3];
    const float* w1   = (const float*)d_in[4];
    const float* b1   = (const float*)d_in[5];
    const float* w2   = (const float*)d_in[6];
    const float* b2   = (const float*)d_in[7];
    float* out = (float*)d_out;
    float* ws  = (float*)d_ws;

    prep_kernel<<<1, BLK, 0, stream>>>((const unsigned int*)mask,
                                       w0, b0, w1, b1, w2, b2, ws);

    const int grid = NPIX / (BLK * PPT);  // 16384
    colormlp_kernel<<<grid, BLK, 0, stream>>>(x, mask, ws, out);
}